// Round 4
// baseline (77.093 us; speedup 1.0000x reference)
//
#include <hip/hip_runtime.h>

#define D256 256
#define KT 8
#define S_SEQ 1024
#define OUTSEQ 512

// ---------------- prep: transpose/pack tables ----------------
// MW[j][o]   = {M[o][j], res_W[o][j]}
// PIt4[j][i] = {P[i][j], 1/p, 2*cos(2pi/p), 0}, p = i*256+j+2
__global__ __launch_bounds__(256) void k_prep(const float* __restrict__ M,
                                              const float* __restrict__ resW,
                                              const float* __restrict__ P,
                                              float2* __restrict__ MW,
                                              float4* __restrict__ PIt4) {
  const int j = blockIdx.x;
  const int t = threadIdx.x;
  MW[j * D256 + t] = make_float2(M[t * D256 + j], resW[t * D256 + j]);
  const float p = (float)(t * D256 + j + 2);
  const float ip = 1.0f / p;                           // precise div
  const float cb2 = 2.0f * __builtin_amdgcn_cosf(ip);  // v_cos takes revolutions
  PIt4[j * D256 + t] = make_float4(P[t * D256 + j], ip, cb2, 0.0f);
}

// ---------------- k_A: x@M^T -> LN -> Z ; x@resW^T -> rfeat ----------------
// KT=8 rows/block, 512 threads = (k-quad q) x (col t); grid 256
__global__ __launch_bounds__(512) void k_A(const float* __restrict__ x,
                                           const float2* __restrict__ MW,
                                           const float* __restrict__ gamma,
                                           const float* __restrict__ beta,
                                           float* __restrict__ Z,
                                           float* __restrict__ rfeat) {
  __shared__ float Xs[KT][D256];        // x tile, then pre-LN accM tile
  __shared__ float mu_s[KT], rs_s[KT];
  const int tid = threadIdx.x;
  const int t = tid & 255;
  const int q = tid >> 8;               // 0/1
  const int r0 = q * 4;
  const int k0 = blockIdx.x * KT;

  #pragma unroll
  for (int r = 0; r < 4; ++r)
    Xs[r0 + r][t] = x[(k0 + r0 + r) * D256 + t];
  __syncthreads();

  float accM[4] = {}, accR[4] = {};
  const float2* mwp = MW + t;
  #pragma unroll 8
  for (int j = 0; j < 256; ++j) {
    const float2 mw = mwp[j * D256];    // both quads load same -> L1 dedup
    #pragma unroll
    for (int r = 0; r < 4; ++r) {
      const float xv = Xs[r0 + r][j];   // wave-broadcast LDS read
      accM[r] = fmaf(xv, mw.x, accM[r]);
      accR[r] = fmaf(xv, mw.y, accR[r]);
    }
  }
  #pragma unroll
  for (int r = 0; r < 4; ++r)
    rfeat[(k0 + r0 + r) * D256 + t] = accR[r];

  __syncthreads();
  #pragma unroll
  for (int r = 0; r < 4; ++r) Xs[r0 + r][t] = accM[r];
  __syncthreads();

  // LN reduce: wave w (of 8) reduces row w
  const int w = tid >> 6, lane = tid & 63;
  {
    float s = 0.f, sq = 0.f;
    #pragma unroll
    for (int l = 0; l < 4; ++l) {
      const float v = Xs[w][lane + 64 * l];
      s += v;
      sq = fmaf(v, v, sq);
    }
    #pragma unroll
    for (int off = 32; off; off >>= 1) {
      s += __shfl_down(s, off);
      sq += __shfl_down(sq, off);
    }
    if (lane == 0) {
      const float m = s * (1.0f / 256.0f);
      const float var = sq * (1.0f / 256.0f) - m * m;
      mu_s[w] = m;
      rs_s[w] = rsqrtf(var + 1e-5f);
    }
  }
  __syncthreads();

  const float g = gamma[t], be = beta[t];
  #pragma unroll
  for (int r = 0; r < 4; ++r) {
    const int kk = r0 + r;
    Z[(k0 + kk) * D256 + t] = (accM[r] - mu_s[kk]) * rs_s[kk] * g + be;
  }
}

// ---------------- k_B: T[k,i] = sum_j Z[k,j]*P[i,j]*cos(2pi*k/p_ij) ----------
// grid 256 (k-tiles of 8), 1024 threads = (j-quarter h) x (i).
// Chebyshev over the k-tile: c_{m+1} = cb2*c_m - c_{m-1}
__global__ __launch_bounds__(1024) void k_B(const float* __restrict__ Z,
                                            const float4* __restrict__ PIt4,
                                            float* __restrict__ T) {
  __shared__ float Zs[KT][D256];        // 8 KB
  __shared__ float red[4][KT][D256];    // 32 KB
  const int tid = threadIdx.x;
  const int i = tid & 255;
  const int h = tid >> 8;               // j-quarter (wave-uniform)
  const int k0 = blockIdx.x * KT;

  ((float*)Zs)[tid]        = Z[k0 * D256 + tid];
  ((float*)Zs)[tid + 1024] = Z[k0 * D256 + 1024 + tid];
  __syncthreads();

  float accT[KT] = {};
  const float kf0 = (float)k0, kf1 = (float)(k0 + 1);
  const float4* pip = PIt4 + h * 64 * D256 + i;
  #pragma unroll 4
  for (int jj = 0; jj < 64; ++jj) {
    const int j = h * 64 + jj;
    const float4 pi = pip[jj * D256];
    float zv[KT];
    #pragma unroll
    for (int kk = 0; kk < KT; ++kk) zv[kk] = Zs[kk][j];   // wave-broadcast
    float r0 = kf0 * pi.y; r0 -= floorf(r0);
    float r1 = kf1 * pi.y; r1 -= floorf(r1);
    float c0 = __builtin_amdgcn_cosf(r0);
    float c1 = __builtin_amdgcn_cosf(r1);
    accT[0] = fmaf(zv[0] * pi.x, c0, accT[0]);
    accT[1] = fmaf(zv[1] * pi.x, c1, accT[1]);
    #pragma unroll
    for (int kk = 2; kk < KT; ++kk) {
      const float c2 = fmaf(pi.z, c1, -c0);
      accT[kk] = fmaf(zv[kk] * pi.x, c2, accT[kk]);
      c0 = c1;
      c1 = c2;
    }
  }

  #pragma unroll
  for (int kk = 0; kk < KT; ++kk) red[h][kk][i] = accT[kk];
  __syncthreads();

  #pragma unroll
  for (int p = 0; p < 2; ++p) {
    const int kk = h + p * 4;
    const float s = red[0][kk][i] + red[1][kk][i] + red[2][kk][i] + red[3][kk][i];
    T[(k0 + kk) * D256 + i] = s;
  }
}

// ---------------- k_C1: split-s GEMM, uniform scalar Linker reads, atomic out
// grid = b(2) x t-tile(64) x s-chunk(8) = 1024 blocks; 256 thr = d
__global__ __launch_bounds__(256) void k_C1(const float* __restrict__ T,
                                            const float* __restrict__ rfeat,
                                            const float* __restrict__ Linker,
                                            const float* __restrict__ rLinker,
                                            float* __restrict__ out) {
  const int bid = blockIdx.x;
  const int sc = bid & 7;
  const int tt = (bid >> 3) & 63;
  const int b  = bid >> 9;
  const int t0 = tt * 8;
  const int s0 = sc * 128;
  const int d  = threadIdx.x;

  float acc[8] = {};
  const float* Tp  = &T[(b * S_SEQ + s0) * D256 + d];
  const float* Rp  = &rfeat[(b * S_SEQ + s0) * D256 + d];
  const float* Lp  = &Linker[s0 * OUTSEQ + t0];    // wave-uniform -> s_load_dwordx8
  const float* rLp = &rLinker[s0 * OUTSEQ + t0];
  #pragma unroll 4
  for (int s = 0; s < 128; ++s) {
    const float tv = Tp[s * D256];
    const float rv = Rp[s * D256];
    #pragma unroll
    for (int u = 0; u < 8; ++u) {
      acc[u] = fmaf(tv, Lp[s * OUTSEQ + u], acc[u]);
      acc[u] = fmaf(rv, rLp[s * OUTSEQ + u], acc[u]);
    }
  }
  const int rowbase = b * 512 + t0;
  #pragma unroll
  for (int u = 0; u < 8; ++u)
    unsafeAtomicAdd(&out[(rowbase + u) * D256 + d], acc[u]);  // HW global_atomic_add_f32
}

extern "C" void kernel_launch(void* const* d_in, const int* in_sizes, int n_in,
                              void* d_out, int out_size, void* d_ws, size_t ws_size,
                              hipStream_t stream) {
  const float* x       = (const float*)d_in[0];
  const float* M       = (const float*)d_in[1];
  const float* P       = (const float*)d_in[2];
  const float* Linker  = (const float*)d_in[3];
  const float* gamma   = (const float*)d_in[4];
  const float* beta    = (const float*)d_in[5];
  const float* resW    = (const float*)d_in[6];
  const float* rLinker = (const float*)d_in[7];
  float* out = (float*)d_out;

  char* ws = (char*)d_ws;
  float2* MW    = (float2*)(ws);                        // 0.5 MB
  float4* PIt4  = (float4*)(ws + 512 * 1024);           // 1 MB
  float*  Zb    = (float*)(ws + 1536 * 1024);           // 2 MB
  float*  T     = (float*)(ws + 3584 * 1024);           // 2 MB
  float*  rfeat = (float*)(ws + 5632 * 1024);           // 2 MB

  hipMemsetAsync(d_out, 0, (size_t)out_size * sizeof(float), stream);
  hipLaunchKernelGGL(k_prep, dim3(256),  dim3(256),  0, stream, M, resW, P, MW, PIt4);
  hipLaunchKernelGGL(k_A,    dim3(256),  dim3(512),  0, stream, x, MW, gamma, beta, Zb, rfeat);
  hipLaunchKernelGGL(k_B,    dim3(256),  dim3(1024), 0, stream, Zb, PIt4, T);
  hipLaunchKernelGGL(k_C1,   dim3(1024), dim3(256),  0, stream, T, rfeat, Linker, rLinker, out);
}

// Round 5
// 61.595 us; speedup vs baseline: 1.2516x; 1.2516x over previous
//
#include <hip/hip_runtime.h>

#define D256 256
#define KT 8
#define S_SEQ 1024
#define OUTSEQ 512

// ---------------- prep: transpose/pack tables ----------------
// MW[j][o]   = {M[o][j], res_W[o][j]}
// PIt4[j][i] = {P[i][j], 1/p, 2*cos(2pi/p), 0}, p = i*256+j+2
__global__ __launch_bounds__(256) void k_prep(const float* __restrict__ M,
                                              const float* __restrict__ resW,
                                              const float* __restrict__ P,
                                              float2* __restrict__ MW,
                                              float4* __restrict__ PIt4) {
  const int j = blockIdx.x;
  const int t = threadIdx.x;
  MW[j * D256 + t] = make_float2(M[t * D256 + j], resW[t * D256 + j]);
  const float p = (float)(t * D256 + j + 2);
  const float ip = 1.0f / p;                           // precise div
  const float cb2 = 2.0f * __builtin_amdgcn_cosf(ip);  // v_cos takes revolutions
  PIt4[j * D256 + t] = make_float4(P[t * D256 + j], ip, cb2, 0.0f);
}

// ---------------- fused k_AB: GEMM -> LN -> cos-einsum, Z never leaves LDS --
// grid 256 (k-tiles of 8), 1024 threads = (j-quarter h) x (col i)
__global__ __launch_bounds__(1024, 4) void k_AB(const float* __restrict__ x,
                                                const float2* __restrict__ MW,
                                                const float4* __restrict__ PIt4,
                                                const float* __restrict__ gamma,
                                                const float* __restrict__ beta,
                                                float* __restrict__ T,
                                                float* __restrict__ rfeat) {
  __shared__ float Xs[D256][12];        // [col][row] padded: b128 rows, 12 KB
  __shared__ float red[4][KT][D256];    // 32 KB reduce buffer (reused 3x)
  __shared__ float mu_s[KT], rs_s[KT];
  const int tid = threadIdx.x;
  const int i = tid & 255;
  const int h = tid >> 8;               // j-quarter, wave-uniform
  const int j0 = h * 64;
  const int k0 = blockIdx.x * KT;

  // stage x tile transposed: [col][row]
  Xs[i][h]     = x[(k0 + h) * D256 + i];
  Xs[i][h + 4] = x[(k0 + h + 4) * D256 + i];
  __syncthreads();

  // ---- phase A: partial x@M^T and x@resW^T over j-quarter ----
  float aM[KT], aR[KT];
  #pragma unroll
  for (int r = 0; r < KT; ++r) { aM[r] = 0.f; aR[r] = 0.f; }
  {
    const float2* mwp = MW + i;
    #pragma unroll 8
    for (int jj = 0; jj < 64; ++jj) {
      const int j = j0 + jj;
      const float2 mw = mwp[j * D256];
      const float4 z0 = *(const float4*)&Xs[j][0];   // broadcast b128
      const float4 z1 = *(const float4*)&Xs[j][4];
      aM[0] = fmaf(z0.x, mw.x, aM[0]); aR[0] = fmaf(z0.x, mw.y, aR[0]);
      aM[1] = fmaf(z0.y, mw.x, aM[1]); aR[1] = fmaf(z0.y, mw.y, aR[1]);
      aM[2] = fmaf(z0.z, mw.x, aM[2]); aR[2] = fmaf(z0.z, mw.y, aR[2]);
      aM[3] = fmaf(z0.w, mw.x, aM[3]); aR[3] = fmaf(z0.w, mw.y, aR[3]);
      aM[4] = fmaf(z1.x, mw.x, aM[4]); aR[4] = fmaf(z1.x, mw.y, aR[4]);
      aM[5] = fmaf(z1.y, mw.x, aM[5]); aR[5] = fmaf(z1.y, mw.y, aR[5]);
      aM[6] = fmaf(z1.z, mw.x, aM[6]); aR[6] = fmaf(z1.z, mw.y, aR[6]);
      aM[7] = fmaf(z1.w, mw.x, aM[7]); aR[7] = fmaf(z1.w, mw.y, aR[7]);
    }
  }

  // reduce aR across quarters -> rfeat
  #pragma unroll
  for (int r = 0; r < KT; ++r) red[h][r][i] = aR[r];
  __syncthreads();
  #pragma unroll
  for (int p = 0; p < 2; ++p) {
    const int r = h * 2 + p;
    rfeat[(k0 + r) * D256 + i] =
        red[0][r][i] + red[1][r][i] + red[2][r][i] + red[3][r][i];
  }
  __syncthreads();

  // reduce aM -> pre-LN Z into Xs (x tile is dead now)
  #pragma unroll
  for (int r = 0; r < KT; ++r) red[h][r][i] = aM[r];
  __syncthreads();
  #pragma unroll
  for (int p = 0; p < 2; ++p) {
    const int r = h * 2 + p;
    Xs[i][r] = red[0][r][i] + red[1][r][i] + red[2][r][i] + red[3][r][i];
  }
  __syncthreads();

  // LN stats: wave w reduces row w
  const int w = tid >> 6, lane = tid & 63;
  if (w < KT) {
    float s = 0.f, sq = 0.f;
    #pragma unroll
    for (int l = 0; l < 4; ++l) {
      const float v = Xs[lane + 64 * l][w];
      s += v;
      sq = fmaf(v, v, sq);
    }
    #pragma unroll
    for (int off = 32; off; off >>= 1) {
      s += __shfl_down(s, off);
      sq += __shfl_down(sq, off);
    }
    if (lane == 0) {
      const float m = s * (1.0f / 256.0f);
      const float var = sq * (1.0f / 256.0f) - m * m;
      mu_s[w] = m;
      rs_s[w] = rsqrtf(var + 1e-5f);
    }
  }
  __syncthreads();
  {
    const float g = gamma[i], be = beta[i];
    #pragma unroll
    for (int p = 0; p < 2; ++p) {
      const int r = h + 4 * p;
      Xs[i][r] = (Xs[i][r] - mu_s[r]) * rs_s[r] * g + be;
    }
  }
  __syncthreads();

  // ---- phase B: T[k,i] = sum_j Z[k,j]*P[i,j]*cos(2pi*k/p_ij), Chebyshev ----
  float accT[KT] = {};
  const float kf0 = (float)k0, kf1 = (float)(k0 + 1);
  {
    const float4* pip = PIt4 + i;
    #pragma unroll 4
    for (int jj = 0; jj < 64; ++jj) {
      const int j = j0 + jj;
      const float4 pi = pip[j * D256];
      const float4 z0 = *(const float4*)&Xs[j][0];   // broadcast b128
      const float4 z1 = *(const float4*)&Xs[j][4];
      float r0 = kf0 * pi.y; r0 -= floorf(r0);
      float r1 = kf1 * pi.y; r1 -= floorf(r1);
      float c0 = __builtin_amdgcn_cosf(r0);
      float c1 = __builtin_amdgcn_cosf(r1);
      accT[0] = fmaf(z0.x * pi.x, c0, accT[0]);
      accT[1] = fmaf(z0.y * pi.x, c1, accT[1]);
      float c2;
      c2 = fmaf(pi.z, c1, -c0); accT[2] = fmaf(z0.z * pi.x, c2, accT[2]); c0 = c1; c1 = c2;
      c2 = fmaf(pi.z, c1, -c0); accT[3] = fmaf(z0.w * pi.x, c2, accT[3]); c0 = c1; c1 = c2;
      c2 = fmaf(pi.z, c1, -c0); accT[4] = fmaf(z1.x * pi.x, c2, accT[4]); c0 = c1; c1 = c2;
      c2 = fmaf(pi.z, c1, -c0); accT[5] = fmaf(z1.y * pi.x, c2, accT[5]); c0 = c1; c1 = c2;
      c2 = fmaf(pi.z, c1, -c0); accT[6] = fmaf(z1.z * pi.x, c2, accT[6]); c0 = c1; c1 = c2;
      c2 = fmaf(pi.z, c1, -c0); accT[7] = fmaf(z1.w * pi.x, c2, accT[7]);
    }
  }
  #pragma unroll
  for (int r = 0; r < KT; ++r) red[h][r][i] = accT[r];
  __syncthreads();
  #pragma unroll
  for (int p = 0; p < 2; ++p) {
    const int r = h * 2 + p;
    T[(k0 + r) * D256 + i] =
        red[0][r][i] + red[1][r][i] + red[2][r][i] + red[3][r][i];
  }
}

// ---------------- stage C1: split-s partial GEMM (round-2 known-good) ------
__global__ __launch_bounds__(256) void k_C1(const float* __restrict__ T,
                                            const float* __restrict__ rfeat,
                                            const float* __restrict__ Linker,
                                            const float* __restrict__ rLinker,
                                            float* __restrict__ part) {
  __shared__ float Ls[128][8];
  __shared__ float rLs[128][8];
  const int bid = blockIdx.x;
  const int sc = bid & 7;
  const int tt = (bid >> 3) & 63;
  const int b  = bid >> 9;
  const int t0 = tt * 8;
  const int s0 = sc * 128;
  const int d  = threadIdx.x;

  {
    const int row = threadIdx.x >> 1;
    const int c4  = (threadIdx.x & 1) * 4;
    *(float4*)&Ls[row][c4]  = *(const float4*)&Linker[(s0 + row) * OUTSEQ + t0 + c4];
    *(float4*)&rLs[row][c4] = *(const float4*)&rLinker[(s0 + row) * OUTSEQ + t0 + c4];
  }
  __syncthreads();

  float acc[8] = {};
  const float* Tp = &T[(b * S_SEQ + s0) * D256 + d];
  const float* Rp = &rfeat[(b * S_SEQ + s0) * D256 + d];
  #pragma unroll 4
  for (int s = 0; s < 128; ++s) {
    const float tv = Tp[s * D256];
    const float rv = Rp[s * D256];
    const float4 l0 = *(const float4*)&Ls[s][0];
    const float4 l1 = *(const float4*)&Ls[s][4];
    const float4 r0 = *(const float4*)&rLs[s][0];
    const float4 r1 = *(const float4*)&rLs[s][4];
    acc[0] = fmaf(tv, l0.x, acc[0]); acc[0] = fmaf(rv, r0.x, acc[0]);
    acc[1] = fmaf(tv, l0.y, acc[1]); acc[1] = fmaf(rv, r0.y, acc[1]);
    acc[2] = fmaf(tv, l0.z, acc[2]); acc[2] = fmaf(rv, r0.z, acc[2]);
    acc[3] = fmaf(tv, l0.w, acc[3]); acc[3] = fmaf(rv, r0.w, acc[3]);
    acc[4] = fmaf(tv, l1.x, acc[4]); acc[4] = fmaf(rv, r1.x, acc[4]);
    acc[5] = fmaf(tv, l1.y, acc[5]); acc[5] = fmaf(rv, r1.y, acc[5]);
    acc[6] = fmaf(tv, l1.z, acc[6]); acc[6] = fmaf(rv, r1.z, acc[6]);
    acc[7] = fmaf(tv, l1.w, acc[7]); acc[7] = fmaf(rv, r1.w, acc[7]);
  }

  const int rowbase = b * 512 + t0;
  #pragma unroll
  for (int u = 0; u < 8; ++u)
    part[(((sc << 10) + rowbase + u) << 8) + d] = acc[u];
}

// ---------------- stage C2: reduce the 8 s-chunk partials ----------------
__global__ __launch_bounds__(256) void k_C2(const float* __restrict__ part,
                                            float* __restrict__ out) {
  const int row = blockIdx.x;   // 0..1023
  const int d   = threadIdx.x;
  float s = 0.f;
  #pragma unroll
  for (int sc = 0; sc < 8; ++sc)
    s += part[(((sc << 10) + row) << 8) + d];
  out[(row << 8) + d] = s;
}

extern "C" void kernel_launch(void* const* d_in, const int* in_sizes, int n_in,
                              void* d_out, int out_size, void* d_ws, size_t ws_size,
                              hipStream_t stream) {
  const float* x       = (const float*)d_in[0];
  const float* M       = (const float*)d_in[1];
  const float* P       = (const float*)d_in[2];
  const float* Linker  = (const float*)d_in[3];
  const float* gamma   = (const float*)d_in[4];
  const float* beta    = (const float*)d_in[5];
  const float* resW    = (const float*)d_in[6];
  const float* rLinker = (const float*)d_in[7];
  float* out = (float*)d_out;

  char* ws = (char*)d_ws;
  float2* MW    = (float2*)(ws);                        // 0.5 MB
  float4* PIt4  = (float4*)(ws + 512 * 1024);           // 1 MB
  float*  T     = (float*)(ws + 1536 * 1024);           // 2 MB
  float*  rfeat = (float*)(ws + 3584 * 1024);           // 2 MB
  float*  part  = (float*)(ws + 5632 * 1024);           // 8 MB

  hipLaunchKernelGGL(k_prep, dim3(256),  dim3(256),  0, stream, M, resW, P, MW, PIt4);
  hipLaunchKernelGGL(k_AB,   dim3(256),  dim3(1024), 0, stream, x, MW, PIt4, gamma, beta, T, rfeat);
  hipLaunchKernelGGL(k_C1,   dim3(1024), dim3(256),  0, stream, T, rfeat, Linker, rLinker, part);
  hipLaunchKernelGGL(k_C2,   dim3(1024), dim3(256),  0, stream, part, out);
}